// Round 1
// baseline (2390.047 us; speedup 1.0000x reference)
//
#include <hip/hip_runtime.h>
#include <hip/hip_bf16.h>
#include <stdint.h>

typedef __bf16 bf16;
typedef __bf16 bf16x8 __attribute__((ext_vector_type(8)));
typedef float f32x4 __attribute__((ext_vector_type(4)));

// address-space-cast helpers for global_load_lds (CK-style cast via uintptr_t)
typedef uint32_t __attribute__((address_space(1))) * gptr_as1;
typedef uint32_t __attribute__((address_space(3))) * lptr_as3;

__device__ __forceinline__ void async16(const void* g, void* l) {
    __builtin_amdgcn_global_load_lds((gptr_as1)(uintptr_t)g,
                                     (lptr_as3)(uintptr_t)l,
                                     16, 0, 0);
}

// ---------------------------------------------------------------- cvt f32->bf16
__global__ void cvt_f32_bf16_kernel(const float* __restrict__ src,
                                    bf16* __restrict__ dst, int n8) {
    int i = blockIdx.x * blockDim.x + threadIdx.x;
    if (i >= n8) return;
    const float4* s = reinterpret_cast<const float4*>(src);
    float4 a = s[2 * (size_t)i], b = s[2 * (size_t)i + 1];
    bf16x8 v;
    v[0] = (bf16)a.x; v[1] = (bf16)a.y; v[2] = (bf16)a.z; v[3] = (bf16)a.w;
    v[4] = (bf16)b.x; v[5] = (bf16)b.y; v[6] = (bf16)b.z; v[7] = (bf16)b.w;
    *reinterpret_cast<bf16x8*>(dst + (size_t)i * 8) = v;
}

// ---------------------------------------------------------------- fused GEMM1+2 + SwiGLU
// C[t,h] tile 128x128, BK=64, 4 waves (2x2), acc 4x4 frags of 16x16x32 bf16 MFMA.
// A = x [M,K], B1 = W1 [N,K], B2 = W2 [N,K]; H = silu(A*B1^T*s1) * (A*B2^T*s2) as bf16.
__global__ __launch_bounds__(256, 2)
void gemm12_swiglu(const bf16* __restrict__ A, const bf16* __restrict__ B1,
                   const bf16* __restrict__ B2, bf16* __restrict__ H,
                   const float* __restrict__ s1p, const float* __restrict__ s2p,
                   int N, int K) {
    __shared__ __align__(16) bf16 As[128][64];
    __shared__ __align__(16) bf16 B1s[128][64];
    __shared__ __align__(16) bf16 B2s[128][64];

    const int tid = threadIdx.x;
    const int w = tid >> 6, l = tid & 63;
    const int bn = blockIdx.x, bm = blockIdx.y;
    const int wr = w >> 1, wc = w & 1;

    f32x4 acc1[4][4] = {};
    f32x4 acc2[4][4] = {};

    // staging: round r, wave w, lane l -> LDS byte w*1024 + r*4096 + l*16
    // == row (r*32 + w*8 + l/8), col (l%8)*8 of the [128][64] tile
    const int srow = w * 8 + (l >> 3);
    const int scol = (l & 7) * 8;
    const bf16* Ab  = A  + (size_t)(bm * 128 + srow) * K + scol;
    const bf16* B1b = B1 + (size_t)(bn * 128 + srow) * K + scol;
    const bf16* B2b = B2 + (size_t)(bn * 128 + srow) * K + scol;
    char* AsB  = (char*)&As[0][0]  + w * 1024;
    char* B1sB = (char*)&B1s[0][0] + w * 1024;
    char* B2sB = (char*)&B2s[0][0] + w * 1024;

    for (int k0 = 0; k0 < K; k0 += 64) {
#pragma unroll
        for (int r = 0; r < 4; ++r) {
            async16(Ab  + (size_t)r * 32 * K + k0, AsB  + r * 4096);
            async16(B1b + (size_t)r * 32 * K + k0, B1sB + r * 4096);
            async16(B2b + (size_t)r * 32 * K + k0, B2sB + r * 4096);
        }
        __syncthreads();
#pragma unroll
        for (int kk = 0; kk < 64; kk += 32) {
            const int kc = kk + (l >> 4) * 8;
            const int rr = l & 15;
            bf16x8 av[4], b1v[4], b2v[4];
#pragma unroll
            for (int i = 0; i < 4; ++i)
                av[i] = *reinterpret_cast<const bf16x8*>(&As[wr * 64 + i * 16 + rr][kc]);
#pragma unroll
            for (int j = 0; j < 4; ++j)
                b1v[j] = *reinterpret_cast<const bf16x8*>(&B1s[wc * 64 + j * 16 + rr][kc]);
#pragma unroll
            for (int j = 0; j < 4; ++j)
                b2v[j] = *reinterpret_cast<const bf16x8*>(&B2s[wc * 64 + j * 16 + rr][kc]);
#pragma unroll
            for (int i = 0; i < 4; ++i)
#pragma unroll
                for (int j = 0; j < 4; ++j) {
                    acc1[i][j] = __builtin_amdgcn_mfma_f32_16x16x32_bf16(av[i], b1v[j], acc1[i][j], 0, 0, 0);
                    acc2[i][j] = __builtin_amdgcn_mfma_f32_16x16x32_bf16(av[i], b2v[j], acc2[i][j], 0, 0, 0);
                }
        }
        __syncthreads();
    }

    // epilogue: C/D layout col = lane&15, row = (lane>>4)*4 + q  [m89/m91 verified]
    const float s1 = s1p[0], s2 = s2p[0];
    const int row0 = bm * 128 + wr * 64 + (l >> 4) * 4;
    const int col0 = bn * 128 + wc * 64 + (l & 15);
#pragma unroll
    for (int i = 0; i < 4; ++i)
#pragma unroll
        for (int j = 0; j < 4; ++j)
#pragma unroll
            for (int q = 0; q < 4; ++q) {
                float g = acc1[i][j][q] * s1;
                float v = acc2[i][j][q] * s2;
                float sig = 1.0f / (1.0f + __expf(-g));
                H[(size_t)(row0 + i * 16 + q) * N + (col0 + j * 16)] = (bf16)(g * sig * v);
            }
}

// ---------------------------------------------------------------- generic B^T GEMM
// EPI=0: C = bf16(gelu_exact(acc*s));  EPI=1: C = f32(acc*s)
template <int EPI>
__global__ __launch_bounds__(256, 2)
void gemm_bt(const bf16* __restrict__ A, const bf16* __restrict__ B,
             void* __restrict__ Cout, const float* __restrict__ sp,
             int N, int K) {
    __shared__ __align__(16) bf16 As[128][64];
    __shared__ __align__(16) bf16 Bs[128][64];

    const int tid = threadIdx.x;
    const int w = tid >> 6, l = tid & 63;
    const int bn = blockIdx.x, bm = blockIdx.y;
    const int wr = w >> 1, wc = w & 1;

    f32x4 acc[4][4] = {};

    const int srow = w * 8 + (l >> 3);
    const int scol = (l & 7) * 8;
    const bf16* Ab = A + (size_t)(bm * 128 + srow) * K + scol;
    const bf16* Bb = B + (size_t)(bn * 128 + srow) * K + scol;
    char* AsB = (char*)&As[0][0] + w * 1024;
    char* BsB = (char*)&Bs[0][0] + w * 1024;

    for (int k0 = 0; k0 < K; k0 += 64) {
#pragma unroll
        for (int r = 0; r < 4; ++r) {
            async16(Ab + (size_t)r * 32 * K + k0, AsB + r * 4096);
            async16(Bb + (size_t)r * 32 * K + k0, BsB + r * 4096);
        }
        __syncthreads();
#pragma unroll
        for (int kk = 0; kk < 64; kk += 32) {
            const int kc = kk + (l >> 4) * 8;
            const int rr = l & 15;
            bf16x8 av[4], bv[4];
#pragma unroll
            for (int i = 0; i < 4; ++i)
                av[i] = *reinterpret_cast<const bf16x8*>(&As[wr * 64 + i * 16 + rr][kc]);
#pragma unroll
            for (int j = 0; j < 4; ++j)
                bv[j] = *reinterpret_cast<const bf16x8*>(&Bs[wc * 64 + j * 16 + rr][kc]);
#pragma unroll
            for (int i = 0; i < 4; ++i)
#pragma unroll
                for (int j = 0; j < 4; ++j)
                    acc[i][j] = __builtin_amdgcn_mfma_f32_16x16x32_bf16(av[i], bv[j], acc[i][j], 0, 0, 0);
        }
        __syncthreads();
    }

    const float s = sp[0];
    const int row0 = bm * 128 + wr * 64 + (l >> 4) * 4;
    const int col0 = bn * 128 + wc * 64 + (l & 15);
#pragma unroll
    for (int i = 0; i < 4; ++i)
#pragma unroll
        for (int j = 0; j < 4; ++j)
#pragma unroll
            for (int q = 0; q < 4; ++q) {
                float v = acc[i][j][q] * s;
                size_t idx = (size_t)(row0 + i * 16 + q) * N + (col0 + j * 16);
                if constexpr (EPI == 0) {
                    float g = 0.5f * v * (1.0f + erff(v * 0.70710678118654752f));
                    ((bf16*)Cout)[idx] = (bf16)g;
                } else {
                    ((float*)Cout)[idx] = v;
                }
            }
}

// ---------------------------------------------------------------- launch
extern "C" void kernel_launch(void* const* d_in, const int* in_sizes, int n_in,
                              void* d_out, int out_size, void* d_ws, size_t ws_size,
                              hipStream_t stream) {
    constexpr int NTOK = 8192, DIN = 2048, DHID = 8192;

    const float* x  = (const float*)d_in[0];
    const float* W1 = (const float*)d_in[1];
    const float* W2 = (const float*)d_in[2];
    const float* Wh = (const float*)d_in[3];
    const float* W3 = (const float*)d_in[4];
    const float* s1 = (const float*)d_in[5];
    const float* s2 = (const float*)d_in[6];
    const float* sh = (const float*)d_in[7];
    const float* s3 = (const float*)d_in[8];
    float* out = (float*)d_out;

    char* ws = (char*)d_ws;
    size_t off = 0;
    bf16* xb  = (bf16*)(ws + off); off += (size_t)NTOK * DIN * 2;   // 33.5 MB
    bf16* w1b = (bf16*)(ws + off); off += (size_t)DHID * DIN * 2;   // 33.5 MB
    bf16* w2b = (bf16*)(ws + off); off += (size_t)DHID * DIN * 2;   // 33.5 MB
    bf16* w3b = (bf16*)(ws + off); off += (size_t)DIN * DHID * 2;   // 33.5 MB
    bf16* whb = (bf16*)(ws + off); off += (size_t)DHID * DHID * 2;  // 134 MB
    bf16* h1  = (bf16*)(ws + off); off += (size_t)NTOK * DHID * 2;  // 134 MB
    bf16* h2  = (bf16*)(ws + off); off += (size_t)NTOK * DHID * 2;  // 134 MB
    if (ws_size < off) return;  // 512 MiB required

    auto cvt = [&](const float* s, bf16* d, size_t n) {
        int n8 = (int)(n / 8);
        cvt_f32_bf16_kernel<<<(n8 + 255) / 256, 256, 0, stream>>>(s, d, n8);
    };
    cvt(x,  xb,  (size_t)NTOK * DIN);
    cvt(W1, w1b, (size_t)DHID * DIN);
    cvt(W2, w2b, (size_t)DHID * DIN);
    cvt(W3, w3b, (size_t)DIN * DHID);
    cvt(Wh, whb, (size_t)DHID * DHID);

    gemm12_swiglu<<<dim3(DHID / 128, NTOK / 128), 256, 0, stream>>>(
        xb, w1b, w2b, h1, s1, s2, DHID, DIN);
    gemm_bt<0><<<dim3(DHID / 128, NTOK / 128), 256, 0, stream>>>(
        h1, whb, h2, sh, DHID, DHID);
    gemm_bt<1><<<dim3(DIN / 128, NTOK / 128), 256, 0, stream>>>(
        h2, w3b, out, s3, DIN, DHID);
}

// Round 2
// 1886.074 us; speedup vs baseline: 1.2672x; 1.2672x over previous
//
#include <hip/hip_runtime.h>
#include <hip/hip_bf16.h>
#include <stdint.h>

typedef __bf16 bf16;
typedef __bf16 bf16x8 __attribute__((ext_vector_type(8)));
typedef float f32x4 __attribute__((ext_vector_type(4)));

typedef uint32_t __attribute__((address_space(1))) * gptr_as1;
typedef uint32_t __attribute__((address_space(3))) * lptr_as3;

__device__ __forceinline__ void async16(const void* g, void* l) {
    __builtin_amdgcn_global_load_lds((gptr_as1)(uintptr_t)g,
                                     (lptr_as3)(uintptr_t)l,
                                     16, 0, 0);
}

__device__ __forceinline__ void bar() {
    asm volatile("" ::: "memory");
    __builtin_amdgcn_s_barrier();
    asm volatile("" ::: "memory");
}

// ---------------------------------------------------------------- cvt f32->bf16
__global__ void cvt_f32_bf16_kernel(const float* __restrict__ src,
                                    bf16* __restrict__ dst, int n8) {
    int i = blockIdx.x * blockDim.x + threadIdx.x;
    if (i >= n8) return;
    const float4* s = reinterpret_cast<const float4*>(src);
    float4 a = s[2 * (size_t)i], b = s[2 * (size_t)i + 1];
    bf16x8 v;
    v[0] = (bf16)a.x; v[1] = (bf16)a.y; v[2] = (bf16)a.z; v[3] = (bf16)a.w;
    v[4] = (bf16)b.x; v[5] = (bf16)b.y; v[6] = (bf16)b.z; v[7] = (bf16)b.w;
    *reinterpret_cast<bf16x8*>(dst + (size_t)i * 8) = v;
}

// ---------------------------------------------------------------- fused GEMM1+2 + SwiGLU (unchanged, 128^2 2-phase)
__global__ __launch_bounds__(256, 2)
void gemm12_swiglu(const bf16* __restrict__ A, const bf16* __restrict__ B1,
                   const bf16* __restrict__ B2, bf16* __restrict__ H,
                   const float* __restrict__ s1p, const float* __restrict__ s2p,
                   int N, int K) {
    __shared__ __align__(16) bf16 As[128][64];
    __shared__ __align__(16) bf16 B1s[128][64];
    __shared__ __align__(16) bf16 B2s[128][64];

    const int tid = threadIdx.x;
    const int w = tid >> 6, l = tid & 63;
    const int bn = blockIdx.x, bm = blockIdx.y;
    const int wr = w >> 1, wc = w & 1;

    f32x4 acc1[4][4] = {};
    f32x4 acc2[4][4] = {};

    const int srow = w * 8 + (l >> 3);
    const int scol = (l & 7) * 8;
    const bf16* Ab  = A  + (size_t)(bm * 128 + srow) * K + scol;
    const bf16* B1b = B1 + (size_t)(bn * 128 + srow) * K + scol;
    const bf16* B2b = B2 + (size_t)(bn * 128 + srow) * K + scol;
    char* AsB  = (char*)&As[0][0]  + w * 1024;
    char* B1sB = (char*)&B1s[0][0] + w * 1024;
    char* B2sB = (char*)&B2s[0][0] + w * 1024;

    for (int k0 = 0; k0 < K; k0 += 64) {
#pragma unroll
        for (int r = 0; r < 4; ++r) {
            async16(Ab  + (size_t)r * 32 * K + k0, AsB  + r * 4096);
            async16(B1b + (size_t)r * 32 * K + k0, B1sB + r * 4096);
            async16(B2b + (size_t)r * 32 * K + k0, B2sB + r * 4096);
        }
        __syncthreads();
#pragma unroll
        for (int kk = 0; kk < 64; kk += 32) {
            const int kc = kk + (l >> 4) * 8;
            const int rr = l & 15;
            bf16x8 av[4], b1v[4], b2v[4];
#pragma unroll
            for (int i = 0; i < 4; ++i)
                av[i] = *reinterpret_cast<const bf16x8*>(&As[wr * 64 + i * 16 + rr][kc]);
#pragma unroll
            for (int j = 0; j < 4; ++j)
                b1v[j] = *reinterpret_cast<const bf16x8*>(&B1s[wc * 64 + j * 16 + rr][kc]);
#pragma unroll
            for (int j = 0; j < 4; ++j)
                b2v[j] = *reinterpret_cast<const bf16x8*>(&B2s[wc * 64 + j * 16 + rr][kc]);
#pragma unroll
            for (int i = 0; i < 4; ++i)
#pragma unroll
                for (int j = 0; j < 4; ++j) {
                    acc1[i][j] = __builtin_amdgcn_mfma_f32_16x16x32_bf16(av[i], b1v[j], acc1[i][j], 0, 0, 0);
                    acc2[i][j] = __builtin_amdgcn_mfma_f32_16x16x32_bf16(av[i], b2v[j], acc2[i][j], 0, 0, 0);
                }
        }
        __syncthreads();
    }

    const float s1 = s1p[0], s2 = s2p[0];
    const int row0 = bm * 128 + wr * 64 + (l >> 4) * 4;
    const int col0 = bn * 128 + wc * 64 + (l & 15);
#pragma unroll
    for (int i = 0; i < 4; ++i)
#pragma unroll
        for (int j = 0; j < 4; ++j)
#pragma unroll
            for (int q = 0; q < 4; ++q) {
                float g = acc1[i][j][q] * s1;
                float v = acc2[i][j][q] * s2;
                float sig = 1.0f / (1.0f + __expf(-g));
                H[(size_t)(row0 + i * 16 + q) * N + (col0 + j * 16)] = (bf16)(g * sig * v);
            }
}

// ---------------------------------------------------------------- 256^2 8-phase GEMM (m201 template port)
// C[M,N] = A[M,K] * B[N,K]^T, M,N mult of 256, K mult of 64, K/64 >= 3.
// EPI=0: bf16(gelu_exact(acc*s));  EPI=1: f32(acc*s)
// LDS per buffer: A[256][64] bf16 (32KB) + B[256][64] (32KB); 2 buffers = 128KB.
// Swizzle: lds_byte = row*128 + (colb ^ ((row&7)<<4)); gload_lds dest linear,
// source pre-swizzled (rule #21).
template <int EPI>
__global__ __launch_bounds__(512, 1)
void gemm8p(const bf16* __restrict__ A, const bf16* __restrict__ B,
            void* __restrict__ Cout, const float* __restrict__ sp,
            int N, int K) {
    __shared__ __align__(16) char sm[131072];

    const int tid = threadIdx.x;
    const int w = tid >> 6, l = tid & 63;
    const int wr = w >> 2, wc = w & 3;   // 2 x 4 wave grid; wave tile 128 x 64

    // XCD-aware bijective swizzle (nwg is a multiple of 8 for all our shapes)
    const int gx = gridDim.x;
    const int nwg = gx * (int)gridDim.y;
    const int orig = blockIdx.y * gx + blockIdx.x;
    const int wg = (orig & 7) * (nwg >> 3) + (orig >> 3);
    const int bm = wg / gx, bn = wg % gx;

    const int NT = K >> 6;

    f32x4 acc[8][4] = {};

    char* const bufA0 = sm;
    char* const bufB0 = sm + 32768;
    char* const bufA1 = sm + 65536;
    char* const bufB1 = sm + 98304;
    const int arow = bm * 256, brow = bn * 256;

    // staging: one call = one 64-row slab (8KB), all 8 waves each write w*1024+lane*16.
    // LDS dest linear; global source column pre-swizzled by ((row&7)<<4).
    const int srow_in = l >> 3;                    // 0..7
    const int scolb = ((l & 7) ^ srow_in) << 4;    // source byte col, 16B aligned
    auto STAGE = [&](char* ldsT, const bf16* g, int grow0, int kt, int r0) {
        const int rr = r0 + w * 8 + srow_in;       // (rr&7)==srow_in (r0, w*8 mult of 8)
        const char* gp = (const char*)(g + (size_t)(grow0 + rr) * K + kt * 64) + scolb;
        async16(gp, ldsT + r0 * 128 + w * 1024);
    };

    const int rlane = l & 15;
    const int chi = (l >> 4) << 4;                 // 0,16,32,48 byte
    auto FRAG = [&](const char* tb, int row, int ks) -> bf16x8 {
        const int cb = (ks * 64 + chi) ^ ((row & 7) << 4);
        return *reinterpret_cast<const bf16x8*>(tb + row * 128 + cb);
    };

    // ---- prologue: kt0 fully (B0,B1,Aev,Aod) -> buf0; kt1 (B0,B1,Aev) -> buf1
    STAGE(bufB0, B, brow, 0, 0);   STAGE(bufB0, B, brow, 0, 64);
    STAGE(bufB0, B, brow, 0, 128); STAGE(bufB0, B, brow, 0, 192);
    STAGE(bufA0, A, arow, 0, 0);   STAGE(bufA0, A, arow, 0, 128);
    STAGE(bufA0, A, arow, 0, 64);  STAGE(bufA0, A, arow, 0, 192);
    STAGE(bufB1, B, brow, 1, 0);   STAGE(bufB1, B, brow, 1, 64);
    STAGE(bufB1, B, brow, 1, 128); STAGE(bufB1, B, brow, 1, 192);
    STAGE(bufA1, A, arow, 1, 0);   STAGE(bufA1, A, arow, 1, 128);
    asm volatile("s_waitcnt vmcnt(6)" ::: "memory");   // kt0's 8 loads landed
    bar();

    for (int kt = 0; kt < NT; ++kt) {
        char* cA = (kt & 1) ? bufA1 : bufA0;
        char* cB = (kt & 1) ? bufB1 : bufB0;
        char* nA = (kt & 1) ? bufA0 : bufA1;

        bf16x8 av[8], bv[8];
        // ---- P1: ds_read all B (8) + A rows lo (8); stage A-odd(kt+1) -> other buf
#pragma unroll
        for (int j = 0; j < 4; ++j)
#pragma unroll
            for (int ks = 0; ks < 2; ++ks)
                bv[j * 2 + ks] = FRAG(cB, wc * 64 + j * 16 + rlane, ks);
#pragma unroll
        for (int i = 0; i < 4; ++i)
#pragma unroll
            for (int ks = 0; ks < 2; ++ks)
                av[i * 2 + ks] = FRAG(cA, wr * 128 + i * 16 + rlane, ks);
        if (kt + 1 < NT) { STAGE(nA, A, arow, kt + 1, 64); STAGE(nA, A, arow, kt + 1, 192); }
        bar();
        asm volatile("s_waitcnt lgkmcnt(0)" ::: "memory");
        __builtin_amdgcn_sched_barrier(0);
        __builtin_amdgcn_s_setprio(1);
#pragma unroll
        for (int i = 0; i < 4; ++i)
#pragma unroll
            for (int j = 0; j < 2; ++j)
#pragma unroll
                for (int ks = 0; ks < 2; ++ks)
                    acc[i][j] = __builtin_amdgcn_mfma_f32_16x16x32_bf16(av[i * 2 + ks], bv[j * 2 + ks], acc[i][j], 0, 0, 0);
        __builtin_amdgcn_s_setprio(0);
        bar();
        // ---- P2: no ds_reads; stage B-h0(kt+2) (rows 0-127, read only in P1)
        if (kt + 2 < NT) { STAGE(cB, B, brow, kt + 2, 0); STAGE(cB, B, brow, kt + 2, 64); }
        bar();
        __builtin_amdgcn_s_setprio(1);
#pragma unroll
        for (int i = 0; i < 4; ++i)
#pragma unroll
            for (int j = 2; j < 4; ++j)
#pragma unroll
                for (int ks = 0; ks < 2; ++ks)
                    acc[i][j] = __builtin_amdgcn_mfma_f32_16x16x32_bf16(av[i * 2 + ks], bv[j * 2 + ks], acc[i][j], 0, 0, 0);
        __builtin_amdgcn_s_setprio(0);
        bar();
        // ---- P3: ds_read A rows hi (8); stage B-h1(kt+2) (rows 128-255)
        bf16x8 ah[8];
#pragma unroll
        for (int i = 0; i < 4; ++i)
#pragma unroll
            for (int ks = 0; ks < 2; ++ks)
                ah[i * 2 + ks] = FRAG(cA, wr * 128 + 64 + i * 16 + rlane, ks);
        if (kt + 2 < NT) { STAGE(cB, B, brow, kt + 2, 128); STAGE(cB, B, brow, kt + 2, 192); }
        bar();
        asm volatile("s_waitcnt lgkmcnt(0)" ::: "memory");
        __builtin_amdgcn_sched_barrier(0);
        __builtin_amdgcn_s_setprio(1);
#pragma unroll
        for (int i = 0; i < 4; ++i)
#pragma unroll
            for (int j = 0; j < 2; ++j)
#pragma unroll
                for (int ks = 0; ks < 2; ++ks)
                    acc[4 + i][j] = __builtin_amdgcn_mfma_f32_16x16x32_bf16(ah[i * 2 + ks], bv[j * 2 + ks], acc[4 + i][j], 0, 0, 0);
        __builtin_amdgcn_s_setprio(0);
        bar();
        // ---- P4: no ds_reads; stage A-even(kt+2) (rows 0-63,128-191, read only in P1)
        if (kt + 2 < NT) { STAGE(cA, A, arow, kt + 2, 0); STAGE(cA, A, arow, kt + 2, 128); }
        bar();
        __builtin_amdgcn_s_setprio(1);
#pragma unroll
        for (int i = 0; i < 4; ++i)
#pragma unroll
            for (int j = 2; j < 4; ++j)
#pragma unroll
                for (int ks = 0; ks < 2; ++ks)
                    acc[4 + i][j] = __builtin_amdgcn_mfma_f32_16x16x32_bf16(ah[i * 2 + ks], bv[j * 2 + ks], acc[4 + i][j], 0, 0, 0);
        __builtin_amdgcn_s_setprio(0);
        if (kt == NT - 2) { asm volatile("s_waitcnt vmcnt(0)" ::: "memory"); }
        else              { asm volatile("s_waitcnt vmcnt(6)" ::: "memory"); }
        bar();
    }

    const float s = sp[0];
    const int r0 = bm * 256 + wr * 128 + ((l >> 4) << 2);
    const int c0 = bn * 256 + wc * 64 + rlane;
#pragma unroll
    for (int i = 0; i < 8; ++i)
#pragma unroll
        for (int j = 0; j < 4; ++j)
#pragma unroll
            for (int q = 0; q < 4; ++q) {
                float v = acc[i][j][q] * s;
                size_t idx = (size_t)(r0 + i * 16 + q) * N + (c0 + j * 16);
                if constexpr (EPI == 0) {
                    float g = 0.5f * v * (1.0f + erff(v * 0.70710678118654752f));
                    ((bf16*)Cout)[idx] = (bf16)g;
                } else {
                    ((float*)Cout)[idx] = v;
                }
            }
}

// ---------------------------------------------------------------- launch
extern "C" void kernel_launch(void* const* d_in, const int* in_sizes, int n_in,
                              void* d_out, int out_size, void* d_ws, size_t ws_size,
                              hipStream_t stream) {
    constexpr int NTOK = 8192, DIN = 2048, DHID = 8192;

    const float* x  = (const float*)d_in[0];
    const float* W1 = (const float*)d_in[1];
    const float* W2 = (const float*)d_in[2];
    const float* Wh = (const float*)d_in[3];
    const float* W3 = (const float*)d_in[4];
    const float* s1 = (const float*)d_in[5];
    const float* s2 = (const float*)d_in[6];
    const float* sh = (const float*)d_in[7];
    const float* s3 = (const float*)d_in[8];
    float* out = (float*)d_out;

    char* ws = (char*)d_ws;
    size_t off = 0;
    bf16* xb  = (bf16*)(ws + off); off += (size_t)NTOK * DIN * 2;
    bf16* w1b = (bf16*)(ws + off); off += (size_t)DHID * DIN * 2;
    bf16* w2b = (bf16*)(ws + off); off += (size_t)DHID * DIN * 2;
    bf16* w3b = (bf16*)(ws + off); off += (size_t)DIN * DHID * 2;
    bf16* whb = (bf16*)(ws + off); off += (size_t)DHID * DHID * 2;
    bf16* h1  = (bf16*)(ws + off); off += (size_t)NTOK * DHID * 2;
    bf16* h2  = (bf16*)(ws + off); off += (size_t)NTOK * DHID * 2;
    if (ws_size < off) return;

    auto cvt = [&](const float* s, bf16* d, size_t n) {
        int n8 = (int)(n / 8);
        cvt_f32_bf16_kernel<<<(n8 + 255) / 256, 256, 0, stream>>>(s, d, n8);
    };
    cvt(x,  xb,  (size_t)NTOK * DIN);
    cvt(W1, w1b, (size_t)DHID * DIN);
    cvt(W2, w2b, (size_t)DHID * DIN);
    cvt(W3, w3b, (size_t)DIN * DHID);
    cvt(Wh, whb, (size_t)DHID * DHID);

    gemm12_swiglu<<<dim3(DHID / 128, NTOK / 128), 256, 0, stream>>>(
        xb, w1b, w2b, h1, s1, s2, DHID, DIN);
    gemm8p<0><<<dim3(DHID / 256, NTOK / 256), 512, 0, stream>>>(
        h1, whb, h2, sh, DHID, DHID);
    gemm8p<1><<<dim3(DIN / 256, NTOK / 256), 512, 0, stream>>>(
        h2, w3b, out, s3, DIN, DHID);
}

// Round 3
// 1762.952 us; speedup vs baseline: 1.3557x; 1.0698x over previous
//
#include <hip/hip_runtime.h>
#include <hip/hip_bf16.h>
#include <stdint.h>

typedef __bf16 bf16;
typedef __bf16 bf16x8 __attribute__((ext_vector_type(8)));
typedef float f32x4 __attribute__((ext_vector_type(4)));

typedef uint32_t __attribute__((address_space(1))) * gptr_as1;
typedef uint32_t __attribute__((address_space(3))) * lptr_as3;

__device__ __forceinline__ void async16(const void* g, void* l) {
    __builtin_amdgcn_global_load_lds((gptr_as1)(uintptr_t)g,
                                     (lptr_as3)(uintptr_t)l,
                                     16, 0, 0);
}

__device__ __forceinline__ void bar() {
    asm volatile("" ::: "memory");
    __builtin_amdgcn_s_barrier();
    asm volatile("" ::: "memory");
}

// ---------------------------------------------------------------- cvt f32->bf16
__global__ void cvt_f32_bf16_kernel(const float* __restrict__ src,
                                    bf16* __restrict__ dst, int n8) {
    int i = blockIdx.x * blockDim.x + threadIdx.x;
    if (i >= n8) return;
    const float4* s = reinterpret_cast<const float4*>(src);
    float4 a = s[2 * (size_t)i], b = s[2 * (size_t)i + 1];
    bf16x8 v;
    v[0] = (bf16)a.x; v[1] = (bf16)a.y; v[2] = (bf16)a.z; v[3] = (bf16)a.w;
    v[4] = (bf16)b.x; v[5] = (bf16)b.y; v[6] = (bf16)b.z; v[7] = (bf16)b.w;
    *reinterpret_cast<bf16x8*>(dst + (size_t)i * 8) = v;
}

// cvt + 16-row interleave: src row r (of DHID) -> dst row (r/16)*32 + sel*16 + r%16.
// DIN = 2048 hardcoded (256 8-elem chunks per row).
__global__ void cvt_ilv_kernel(const float* __restrict__ src,
                               bf16* __restrict__ dst, int n8, int sel) {
    int i = blockIdx.x * blockDim.x + threadIdx.x;
    if (i >= n8) return;
    const int row = i >> 8;          // / 256
    const int c = i & 255;
    const int drow = ((row >> 4) << 5) + (sel << 4) + (row & 15);
    const float4* s = reinterpret_cast<const float4*>(src);
    float4 a = s[2 * (size_t)i], b = s[2 * (size_t)i + 1];
    bf16x8 v;
    v[0] = (bf16)a.x; v[1] = (bf16)a.y; v[2] = (bf16)a.z; v[3] = (bf16)a.w;
    v[4] = (bf16)b.x; v[5] = (bf16)b.y; v[6] = (bf16)b.z; v[7] = (bf16)b.w;
    *reinterpret_cast<bf16x8*>(dst + ((size_t)drow * 256 + c) * 8) = v;
}

// ---------------------------------------------------------------- 256^2 8-phase GEMM
// C = A[M,K] * B[N,K]^T. 512 thr / 8 waves (2x4), wave tile 128x64, BK=64.
// LDS: 2 dbuf x (A 32KB + B 32KB) = 128KB. Swizzle: lds_byte = row*128 + (colb ^ ((row&7)<<4));
// gload_lds dest linear, global source pre-swizzled (rule #21).
// Phase read balance 12/4/8/0; stages: P1 A-odd(kt+1)->other, P2 A-even(kt+2)->cur,
// P3 B-h0(kt+2)->cur, P4 B-h1(kt+2)->cur. vmcnt(6) once per K-tile (0 at NT-2).
// EPI=0: bf16(gelu(acc*s1)) stride N | EPI=1: f32(acc*s1) stride N
// EPI=2: swiglu over 16-col-interleaved gate/value, bf16 out stride ldh, cols N/2.
template <int EPI, int K>
__global__ __launch_bounds__(512, 1)
void gemm8p(const bf16* __restrict__ A, const bf16* __restrict__ B,
            void* __restrict__ Cout, const float* __restrict__ s1p,
            const float* __restrict__ s2p, int N, int ldh) {
    __shared__ __align__(16) char sm[131072];

    const int tid = threadIdx.x;
    const int w = tid >> 6, l = tid & 63;
    const int wr = w >> 2, wc = w & 3;

    const int gx = gridDim.x;
    const int nwg = gx * (int)gridDim.y;
    const int orig = blockIdx.y * gx + blockIdx.x;
    const int wg = (orig & 7) * (nwg >> 3) + (orig >> 3);
    const int bm = wg / gx, bn = wg % gx;

    constexpr int NT = K / 64;

    f32x4 acc[8][4] = {};

    char* const bufA0 = sm;
    char* const bufB0 = sm + 32768;
    char* const bufA1 = sm + 65536;
    char* const bufB1 = sm + 98304;
    const int arow = bm * 256, brow = bn * 256;

    const int srow_in = l >> 3;
    const int scolb = ((l & 7) ^ srow_in) << 4;
    auto STAGE = [&](char* ldsT, const bf16* g, int grow0, int kt, int r0) {
        const int rr = r0 + w * 8 + srow_in;
        const char* gp = (const char*)(g + (size_t)(grow0 + rr) * K + kt * 64) + scolb;
        async16(gp, ldsT + r0 * 128 + w * 1024);
    };

    const int rlane = l & 15;
    const int chi = (l >> 4) << 4;
    auto FRAG = [&](const char* tb, int row, int ks) -> bf16x8 {
        const int cb = (ks * 64 + chi) ^ ((row & 7) << 4);
        return *reinterpret_cast<const bf16x8*>(tb + row * 128 + cb);
    };

    // ---- prologue: kt0 full (8) -> buf0; kt1 {Aev,B0,B1} (6) -> buf1
    STAGE(bufB0, B, brow, 0, 0);   STAGE(bufB0, B, brow, 0, 64);
    STAGE(bufB0, B, brow, 0, 128); STAGE(bufB0, B, brow, 0, 192);
    STAGE(bufA0, A, arow, 0, 0);   STAGE(bufA0, A, arow, 0, 128);
    STAGE(bufA0, A, arow, 0, 64);  STAGE(bufA0, A, arow, 0, 192);
    STAGE(bufA1, A, arow, 1, 0);   STAGE(bufA1, A, arow, 1, 128);
    STAGE(bufB1, B, brow, 1, 0);   STAGE(bufB1, B, brow, 1, 64);
    STAGE(bufB1, B, brow, 1, 128); STAGE(bufB1, B, brow, 1, 192);
    asm volatile("s_waitcnt vmcnt(6)" ::: "memory");
    bar();

    char* cA = bufA0; char* cB = bufB0;
    char* nA = bufA1; char* nB = bufB1;

#pragma unroll 1
    for (int kt = 0; kt < NT; ++kt) {
        bf16x8 avl[8], bvl[4], bvh[4], avh[8];
        // ---- P1 (12 reads): av-lo + bv-lo; stage A-odd(kt+1) -> other buf
#pragma unroll
        for (int i = 0; i < 4; ++i)
#pragma unroll
            for (int ks = 0; ks < 2; ++ks)
                avl[i * 2 + ks] = FRAG(cA, wr * 128 + i * 16 + rlane, ks);
#pragma unroll
        for (int j = 0; j < 2; ++j)
#pragma unroll
            for (int ks = 0; ks < 2; ++ks)
                bvl[j * 2 + ks] = FRAG(cB, wc * 64 + j * 16 + rlane, ks);
        if (kt + 1 < NT) { STAGE(nA, A, arow, kt + 1, 64); STAGE(nA, A, arow, kt + 1, 192); }
        asm volatile("s_waitcnt lgkmcnt(8)" ::: "memory");
        bar();
        asm volatile("s_waitcnt lgkmcnt(0)" ::: "memory");
        __builtin_amdgcn_sched_barrier(0);
        __builtin_amdgcn_s_setprio(1);
#pragma unroll
        for (int i = 0; i < 4; ++i)
#pragma unroll
            for (int j = 0; j < 2; ++j)
#pragma unroll
                for (int ks = 0; ks < 2; ++ks)
                    acc[i][j] = __builtin_amdgcn_mfma_f32_16x16x32_bf16(avl[i * 2 + ks], bvl[j * 2 + ks], acc[i][j], 0, 0, 0);
        __builtin_amdgcn_s_setprio(0);
        bar();
        // ---- P2 (4 reads): bv-hi; stage A-even(kt+2) -> cur
#pragma unroll
        for (int j = 0; j < 2; ++j)
#pragma unroll
            for (int ks = 0; ks < 2; ++ks)
                bvh[j * 2 + ks] = FRAG(cB, wc * 64 + 32 + j * 16 + rlane, ks);
        if (kt + 2 < NT) { STAGE(cA, A, arow, kt + 2, 0); STAGE(cA, A, arow, kt + 2, 128); }
        bar();
        asm volatile("s_waitcnt lgkmcnt(0)" ::: "memory");
        __builtin_amdgcn_sched_barrier(0);
        __builtin_amdgcn_s_setprio(1);
#pragma unroll
        for (int i = 0; i < 4; ++i)
#pragma unroll
            for (int j = 0; j < 2; ++j)
#pragma unroll
                for (int ks = 0; ks < 2; ++ks)
                    acc[i][2 + j] = __builtin_amdgcn_mfma_f32_16x16x32_bf16(avl[i * 2 + ks], bvh[j * 2 + ks], acc[i][2 + j], 0, 0, 0);
        __builtin_amdgcn_s_setprio(0);
        bar();
        // ---- P3 (8 reads): av-hi; stage B-h0(kt+2) -> cur
#pragma unroll
        for (int i = 0; i < 4; ++i)
#pragma unroll
            for (int ks = 0; ks < 2; ++ks)
                avh[i * 2 + ks] = FRAG(cA, wr * 128 + 64 + i * 16 + rlane, ks);
        if (kt + 2 < NT) { STAGE(cB, B, brow, kt + 2, 0); STAGE(cB, B, brow, kt + 2, 64); }
        bar();
        asm volatile("s_waitcnt lgkmcnt(0)" ::: "memory");
        __builtin_amdgcn_sched_barrier(0);
        __builtin_amdgcn_s_setprio(1);
#pragma unroll
        for (int i = 0; i < 4; ++i)
#pragma unroll
            for (int j = 0; j < 2; ++j)
#pragma unroll
                for (int ks = 0; ks < 2; ++ks)
                    acc[4 + i][j] = __builtin_amdgcn_mfma_f32_16x16x32_bf16(avh[i * 2 + ks], bvl[j * 2 + ks], acc[4 + i][j], 0, 0, 0);
        __builtin_amdgcn_s_setprio(0);
        bar();
        // ---- P4 (0 reads): stage B-h1(kt+2) -> cur
        if (kt + 2 < NT) { STAGE(cB, B, brow, kt + 2, 128); STAGE(cB, B, brow, kt + 2, 192); }
        bar();
        __builtin_amdgcn_s_setprio(1);
#pragma unroll
        for (int i = 0; i < 4; ++i)
#pragma unroll
            for (int j = 0; j < 2; ++j)
#pragma unroll
                for (int ks = 0; ks < 2; ++ks)
                    acc[4 + i][2 + j] = __builtin_amdgcn_mfma_f32_16x16x32_bf16(avh[i * 2 + ks], bvh[j * 2 + ks], acc[4 + i][2 + j], 0, 0, 0);
        __builtin_amdgcn_s_setprio(0);
        if (kt == NT - 2) { asm volatile("s_waitcnt vmcnt(0)" ::: "memory"); }
        else              { asm volatile("s_waitcnt vmcnt(6)" ::: "memory"); }
        bar();
        char* t = cA; cA = nA; nA = t;
        t = cB; cB = nB; nB = t;
    }

    const float s1 = s1p[0];
    const int r0 = bm * 256 + wr * 128 + ((l >> 4) << 2);
    if constexpr (EPI == 2) {
        const float s2 = s2p[0];
        const int hcb = (bn * 8 + wc * 2) * 16 + rlane;
#pragma unroll
        for (int i = 0; i < 8; ++i)
#pragma unroll
            for (int jp = 0; jp < 2; ++jp)
#pragma unroll
                for (int q = 0; q < 4; ++q) {
                    float g = acc[i][2 * jp][q] * s1;
                    float v = acc[i][2 * jp + 1][q] * s2;
                    float sig = 1.0f / (1.0f + __expf(-g));
                    ((bf16*)Cout)[(size_t)(r0 + i * 16 + q) * ldh + hcb + jp * 16] =
                        (bf16)(g * sig * v);
                }
    } else {
        const int c0 = bn * 256 + wc * 64 + rlane;
#pragma unroll
        for (int i = 0; i < 8; ++i)
#pragma unroll
            for (int j = 0; j < 4; ++j)
#pragma unroll
                for (int q = 0; q < 4; ++q) {
                    float v = acc[i][j][q] * s1;
                    size_t idx = (size_t)(r0 + i * 16 + q) * N + (c0 + j * 16);
                    if constexpr (EPI == 0) {
                        float g = 0.5f * v * (1.0f + erff(v * 0.70710678118654752f));
                        ((bf16*)Cout)[idx] = (bf16)g;
                    } else {
                        ((float*)Cout)[idx] = v;
                    }
                }
    }
}

// ---------------------------------------------------------------- launch
extern "C" void kernel_launch(void* const* d_in, const int* in_sizes, int n_in,
                              void* d_out, int out_size, void* d_ws, size_t ws_size,
                              hipStream_t stream) {
    constexpr int NTOK = 8192, DIN = 2048, DHID = 8192;

    const float* x  = (const float*)d_in[0];
    const float* W1 = (const float*)d_in[1];
    const float* W2 = (const float*)d_in[2];
    const float* Wh = (const float*)d_in[3];
    const float* W3 = (const float*)d_in[4];
    const float* s1 = (const float*)d_in[5];
    const float* s2 = (const float*)d_in[6];
    const float* sh = (const float*)d_in[7];
    const float* s3 = (const float*)d_in[8];
    float* out = (float*)d_out;

    char* ws = (char*)d_ws;
    size_t off = 0;
    bf16* xb   = (bf16*)(ws + off); off += (size_t)NTOK * DIN * 2;      // 33.5 MB
    bf16* w12b = (bf16*)(ws + off); off += (size_t)2 * DHID * DIN * 2;  // 67 MB
    bf16* w3b  = (bf16*)(ws + off); off += (size_t)DIN * DHID * 2;      // 33.5 MB
    bf16* whb  = (bf16*)(ws + off); off += (size_t)DHID * DHID * 2;     // 134 MB
    bf16* h1   = (bf16*)(ws + off); off += (size_t)NTOK * DHID * 2;     // 134 MB
    bf16* h2   = (bf16*)(ws + off); off += (size_t)NTOK * DHID * 2;     // 134 MB
    if (ws_size < off) return;

    auto cvt = [&](const float* s, bf16* d, size_t n) {
        int n8 = (int)(n / 8);
        cvt_f32_bf16_kernel<<<(n8 + 255) / 256, 256, 0, stream>>>(s, d, n8);
    };
    cvt(x,  xb,  (size_t)NTOK * DIN);
    cvt(Wh, whb, (size_t)DHID * DHID);
    cvt(W3, w3b, (size_t)DIN * DHID);
    {
        int n8 = (int)((size_t)DHID * DIN / 8);
        cvt_ilv_kernel<<<(n8 + 255) / 256, 256, 0, stream>>>(W1, w12b, n8, 0);
        cvt_ilv_kernel<<<(n8 + 255) / 256, 256, 0, stream>>>(W2, w12b, n8, 1);
    }

    // GEMM1+2 fused: C[8192, 16384] over interleaved W12, SwiGLU epilogue -> h1[8192, 8192]
    gemm8p<2, DIN><<<dim3(2 * DHID / 256, NTOK / 256), 512, 0, stream>>>(
        xb, w12b, h1, s1, s2, 2 * DHID, DHID);
    // hidden GEMM + gelu -> h2
    gemm8p<0, DHID><<<dim3(DHID / 256, NTOK / 256), 512, 0, stream>>>(
        h1, whb, h2, sh, sh, DHID, DHID);
    // output GEMM -> out (f32)
    gemm8p<1, DHID><<<dim3(DIN / 256, NTOK / 256), 512, 0, stream>>>(
        h2, w3b, out, s3, s3, DIN, DIN);
}